// Round 9
// baseline (1235.197 us; speedup 1.0000x reference)
//
#include <hip/hip_runtime.h>

#define NN 50000
#define NE 100000
#define NB 500
#define NEP 100096   // 391*256 padded edge count
#define NKF 136      // 34 chunks of 4 (129 real kf rows: 128 + bias)
#define CKF 4

typedef _Float16 half2_t __attribute__((ext_vector_type(2)));
typedef _Float16 half8_t __attribute__((ext_vector_type(8)));
typedef float f32x16 __attribute__((ext_vector_type(16)));

union F8U { half8_t v; uint4 u; };

__device__ __forceinline__ float sigm(float x){ return 1.0f/(1.0f + __expf(-x)); }
__device__ __forceinline__ unsigned short f16u(float f){
  _Float16 h = (_Float16)f; return *(unsigned short*)&h;
}

// ---------------- setup kernels ----------------

__global__ void k_gstart(const int* __restrict__ batch, int* __restrict__ gst){
  int g = blockIdx.x*blockDim.x + threadIdx.x;
  if (g > NB) return;
  if (g == NB){ gst[g] = NN; return; }
  int lo=0, hi=NN;
  while (lo < hi){ int mid=(lo+hi)>>1; if (batch[mid] < g) lo = mid+1; else hi = mid; }
  gst[g] = lo;
}

__global__ void k_deg(const int* __restrict__ dst, float* __restrict__ deg){
  int e = blockIdx.x*blockDim.x + threadIdx.x;
  if (e < NE) atomicAdd(&deg[dst[e]], 1.0f);
}

__global__ void k_rdeg(float* __restrict__ deg){
  int i = blockIdx.x*blockDim.x + threadIdx.x;
  if (i < NN) deg[i] = 1.0f / fmaxf(deg[i], 1.0f);
}

// h1T[j][e] = relu(edge_attr[e] @ w1[j] + b1[j]); row 128 = 1.0 (bias slice)
__global__ void k_h1T(const float* __restrict__ ea, const float* __restrict__ w1,
                      const float* __restrict__ b1, _Float16* __restrict__ h1T){
  int e = blockIdx.x*256 + threadIdx.x;
  int j = blockIdx.y;
  if (e >= NE) return;
  float s;
  if (j == 128){
    s = 1.0f;
  } else {
    const float* a = ea + (size_t)e*7;
    const float* wr = w1 + j*7;
    s = b1[j];
    #pragma unroll
    for (int k=0;k<7;k++) s = fmaf(a[k], wr[k], s);
    s = fmaxf(s, 0.0f);
  }
  h1T[(size_t)j*NEP + e] = (_Float16)s;
}

// out0 = relu(x @ lin0_w.T + b)  [N,64]
__global__ void k_lin0(const float* __restrict__ x, const float* __restrict__ w,
                       const float* __restrict__ b, float* __restrict__ hbuf){
  int idx = blockIdx.x*blockDim.x + threadIdx.x;
  if (idx >= NN*64) return;
  int n = idx >> 6, o = idx & 63;
  const float* xr = x + n*3;
  const float* wr = w + o*3;
  float s = b[o] + xr[0]*wr[0] + xr[1]*wr[1] + xr[2]*wr[2];
  hbuf[idx] = fmaxf(s, 0.0f);
}

// B2s[kf] is an 8KB block: [o=64][i=64] f16, XOR-swizzled byte^((o&7)<<4).
// kf<128: w2[(i*64+o), kf]; kf==128: b2[i*64+o]; kf in 129..135: 0 (pad).
__global__ void k_prepB(const float* __restrict__ w2, const float* __restrict__ b2,
                        _Float16* __restrict__ B2s){
  int idx = blockIdx.x*blockDim.x + threadIdx.x;
  if (idx >= NKF*4096) return;
  int kf = idx >> 12, r = idx & 4095, o = r >> 6, i = r & 63;
  float v = (kf < 128) ? w2[(size_t)(i*64+o)*128 + kf] : (kf == 128 ? b2[i*64+o] : 0.0f);
  int byt = (o*128 + i*2) ^ ((o&7)<<4);
  *(unsigned short*)((char*)B2s + (size_t)kf*8192 + byt) = f16u(v);
}

// Wg = [rootB 8KB][WG 48KB] f16, swizzled.
// rootB[o][k=i] = conv_root[i*64+o]          (byte = (o*128+k*2)^((o&7)<<4))
// WG[o][k]: k<64 -> wih[o*64+k]; k>=64 -> whh[o*64+(k-64)]  (byte = 8192+(o*256+k*2)^((o&7)<<4))
__global__ void k_prepW(const float* __restrict__ root, const float* __restrict__ wih,
                        const float* __restrict__ whh, _Float16* __restrict__ Wg){
  int idx = blockIdx.x*blockDim.x + threadIdx.x;
  if (idx >= 28672) return;
  if (idx < 4096){
    int o = idx >> 6, k = idx & 63;
    int byt = (o*128 + k*2) ^ ((o&7)<<4);
    *(unsigned short*)((char*)Wg + byt) = f16u(root[k*64 + o]);
  } else {
    int x = idx - 4096;
    int o = x >> 7, k = x & 127;
    float v = (k < 64) ? wih[o*64 + k] : whh[o*64 + (k-64)];
    int byt = (o*256 + k*2) ^ ((o&7)<<4);
    *(unsigned short*)((char*)Wg + 8192 + byt) = f16u(v);
  }
}

// ---------------- fused NNConv message GEMM v2 (LDS-staged, NT=4, CKF=4) ----------------
// Block: 256 edges x 64 outputs. 4 waves: (we,wo) in 2x2; wave tile = 4x(32e) x 32o.
// K-loop: 34 chunks of 4 kf; B2 chunk (32KB swizzled) + h1 chunk (2KB) staged in LDS.
// ~35KB LDS -> 4 blocks/CU (16 waves/CU) for latency hiding.
__global__ __launch_bounds__(256) void k_msgemm2(
    const _Float16* __restrict__ h1T, const _Float16* __restrict__ B2s,
    const float* __restrict__ hbuf, const int* __restrict__ src,
    const int* __restrict__ dst, float* __restrict__ agg){
  __shared__ __align__(16) _Float16 Bsh[CKF*4096];   // 32KB
  __shared__ __align__(16) _Float16 h1sh[CKF*256];   // 2KB [kf][e_local]
  __shared__ int dst_s[256];
  const int t = threadIdx.x;
  const int lane = t & 63, wv = t >> 6;
  const int hi = lane >> 5, lm = lane & 31;
  const int we = wv >> 1, wo = wv & 1;
  const int o0 = wo * 32;
  const int e0 = blockIdx.x * 256;
  {
    int eg = e0 + t;
    dst_s[t] = (eg < NE) ? dst[eg] : -1;
  }
  // A-side x fragments for 4 edge tiles (verified xp pattern)
  half8_t xa[4][4];
  #pragma unroll
  for (int tt=0; tt<4; ++tt){
    int eg = e0 + tt*64 + we*32 + lm;
    int sidx = (eg < NE) ? src[eg] : 0;
    const float4* xr = (const float4*)(hbuf + (size_t)sidx*64);
    #pragma unroll
    for (int q=0;q<4;++q){
      float4 a = xr[q*4 + hi*2];
      float4 b = xr[q*4 + hi*2 + 1];
      half8_t h;
      h[0]=(_Float16)a.x; h[1]=(_Float16)a.y; h[2]=(_Float16)a.z; h[3]=(_Float16)a.w;
      h[4]=(_Float16)b.x; h[5]=(_Float16)b.y; h[6]=(_Float16)b.z; h[7]=(_Float16)b.w;
      xa[tt][q] = h;
    }
  }
  f32x16 acc[4] = {};
  for (int c = 0; c < NKF/CKF; ++c){
    __syncthreads();
    // stage B2 chunk: 32KB, 8 rounds of 4KB (lanes consecutive 16B -> conflict-free)
    const char* gB = (const char*)B2s + (size_t)c*(CKF*8192);
    #pragma unroll 4
    for (int r=0;r<8;++r){
      uint4 u = *(const uint4*)(gB + r*4096 + t*16);
      *(uint4*)((char*)Bsh + r*4096 + t*16) = u;
    }
    // stage h1 chunk: 4 rows x 512B (threads 0..127)
    if (t < 128){
      int rr = t >> 5, cc = t & 31;
      uint4 u = *(const uint4*)((const char*)h1T + ((size_t)(c*CKF+rr)*NEP + (size_t)e0)*2 + cc*16);
      *(uint4*)((char*)h1sh + rr*512 + cc*16) = u;
    }
    __syncthreads();
    #pragma unroll
    for (int kf=0; kf<CKF; ++kf){
      _Float16 hv0 = h1sh[kf*256 +       we*32 + lm];
      _Float16 hv1 = h1sh[kf*256 +  64 + we*32 + lm];
      _Float16 hv2 = h1sh[kf*256 + 128 + we*32 + lm];
      _Float16 hv3 = h1sh[kf*256 + 192 + we*32 + lm];
      half8_t b0 = {hv0,hv0,hv0,hv0,hv0,hv0,hv0,hv0};
      half8_t b1 = {hv1,hv1,hv1,hv1,hv1,hv1,hv1,hv1};
      half8_t b2_ = {hv2,hv2,hv2,hv2,hv2,hv2,hv2,hv2};
      half8_t b3 = {hv3,hv3,hv3,hv3,hv3,hv3,hv3,hv3};
      #pragma unroll
      for (int q=0;q<4;++q){
        F8U bf;
        int byt = (((o0+lm)*128 + q*32 + hi*16) ^ ((lm&7)<<4));
        bf.u = *(const uint4*)((const char*)Bsh + kf*8192 + byt);
        acc[0] = __builtin_amdgcn_mfma_f32_32x32x16_f16(xa[0][q]*b0, bf.v, acc[0], 0,0,0);
        acc[1] = __builtin_amdgcn_mfma_f32_32x32x16_f16(xa[1][q]*b1, bf.v, acc[1], 0,0,0);
        acc[2] = __builtin_amdgcn_mfma_f32_32x32x16_f16(xa[2][q]*b2_, bf.v, acc[2], 0,0,0);
        acc[3] = __builtin_amdgcn_mfma_f32_32x32x16_f16(xa[3][q]*b3, bf.v, acc[3], 0,0,0);
      }
    }
  }
  // epilogue: verified C layout row=(r&3)+8*(r>>2)+4*hi, col=lm
  #pragma unroll
  for (int tt=0;tt<4;++tt){
    #pragma unroll
    for (int r=0;r<16;++r){
      int row = (r&3) + 8*(r>>2) + 4*hi;
      int d = dst_s[tt*64 + we*32 + row];
      if (d >= 0) atomicAdd(&agg[(size_t)d*64 + o0 + lm], acc[tt][r]);
    }
  }
}

// ---------------- node update v2: MFMA NNConv-epilogue + GRU ----------------
// Block: 128 nodes, 4 waves x 32-node tiles. Weights (56KB swizzled f16) in LDS.
__global__ __launch_bounds__(256) void k_node2(
    const float* __restrict__ agg, const float* __restrict__ rdeg,
    float* __restrict__ hbuf, const _Float16* __restrict__ Wg,
    const float* __restrict__ cbias, const float* __restrict__ bih,
    const float* __restrict__ bhh){
  __shared__ __align__(16) _Float16 WB[28672];       // rootB [0..4096), WG [4096..28672)
  __shared__ __align__(16) _Float16 mT[4][2048];     // per-wave 32x64 f16, swizzled
  const int t = threadIdx.x;
  const int lane = t & 63, wv = t >> 6;
  const int hi = lane >> 5, lm = lane & 31;
  #pragma unroll 2
  for (int r=0;r<14;++r){
    uint4 u = *(const uint4*)((const char*)Wg + r*4096 + t*16);
    *(uint4*)((char*)WB + r*4096 + t*16) = u;
  }
  const int n0 = blockIdx.x*128 + wv*32;
  // h row fragments (A-side), f32 -> f16
  half8_t ah[4];
  {
    int nr = min(n0 + lm, NN-1);
    const float4* hr = (const float4*)(hbuf + (size_t)nr*64);
    #pragma unroll
    for (int q=0;q<4;++q){
      float4 a = hr[q*4 + hi*2];
      float4 b = hr[q*4 + hi*2 + 1];
      half8_t h;
      h[0]=(_Float16)a.x; h[1]=(_Float16)a.y; h[2]=(_Float16)a.z; h[3]=(_Float16)a.w;
      h[4]=(_Float16)b.x; h[5]=(_Float16)b.y; h[6]=(_Float16)b.z; h[7]=(_Float16)b.w;
      ah[q] = h;
    }
  }
  __syncthreads();
  // stage 1: h @ root  (2 o-tiles)
  f32x16 am[2] = {};
  #pragma unroll
  for (int q=0;q<4;++q){
    #pragma unroll
    for (int ot=0;ot<2;++ot){
      int o = ot*32 + lm;
      F8U bf;
      bf.u = *(const uint4*)((const char*)WB + ((o*128 + q*32 + hi*16) ^ ((o&7)<<4)));
      am[ot] = __builtin_amdgcn_mfma_f32_32x32x16_f16(ah[q], bf.v, am[ot], 0,0,0);
    }
  }
  // epilogue 1: m = relu(agg*rdeg + h@root + cbias); write mT (swizzled f16)
  #pragma unroll
  for (int ot=0;ot<2;++ot){
    int col = ot*32 + lm;
    float cb = cbias[col];
    #pragma unroll
    for (int r=0;r<16;++r){
      int row = (r&3) + 8*(r>>2) + 4*hi;
      int n = min(n0 + row, NN-1);
      float mv = fmaxf(fmaf(agg[(size_t)n*64 + col], rdeg[n], am[ot][r] + cb), 0.0f);
      *(unsigned short*)((char*)&mT[wv][0] + ((row*128 + col*2) ^ ((row&7)<<4))) = f16u(mv);
    }
  }
  __syncthreads();
  // m fragments (A-side)
  half8_t amf[4];
  #pragma unroll
  for (int q=0;q<4;++q){
    F8U v;
    v.u = *(const uint4*)((const char*)&mT[wv][0] + ((lm*128 + q*32 + hi*16) ^ ((lm&7)<<4)));
    amf[q] = v.v;
  }
  // stage 2: gates. aF = fused r,z (o-tiles 0..3); aIN = m@wih_n; aHN = h@whh_n.
  f32x16 aF[4] = {}; f32x16 aIN[2] = {}; f32x16 aHN[2] = {};
  const char* WGp = (const char*)WB + 8192;
  #pragma unroll
  for (int q=0;q<4;++q){
    #pragma unroll
    for (int ot=0;ot<4;++ot){
      int o = ot*32 + lm;
      F8U bf; bf.u = *(const uint4*)(WGp + ((o*256 + q*32 + hi*16) ^ ((o&7)<<4)));
      aF[ot] = __builtin_amdgcn_mfma_f32_32x32x16_f16(amf[q], bf.v, aF[ot], 0,0,0);
    }
    #pragma unroll
    for (int j=0;j<2;++j){
      int o = (4+j)*32 + lm;
      F8U bf; bf.u = *(const uint4*)(WGp + ((o*256 + q*32 + hi*16) ^ ((o&7)<<4)));
      aIN[j] = __builtin_amdgcn_mfma_f32_32x32x16_f16(amf[q], bf.v, aIN[j], 0,0,0);
    }
  }
  #pragma unroll
  for (int q=0;q<4;++q){
    #pragma unroll
    for (int ot=0;ot<4;++ot){
      int o = ot*32 + lm;
      F8U bf; bf.u = *(const uint4*)(WGp + ((o*256 + 128 + q*32 + hi*16) ^ ((o&7)<<4)));
      aF[ot] = __builtin_amdgcn_mfma_f32_32x32x16_f16(ah[q], bf.v, aF[ot], 0,0,0);
    }
    #pragma unroll
    for (int j=0;j<2;++j){
      int o = (4+j)*32 + lm;
      F8U bf; bf.u = *(const uint4*)(WGp + ((o*256 + 128 + q*32 + hi*16) ^ ((o&7)<<4)));
      aHN[j] = __builtin_amdgcn_mfma_f32_32x32x16_f16(ah[q], bf.v, aHN[j], 0,0,0);
    }
  }
  // gate math + h update
  #pragma unroll
  for (int j=0;j<2;++j){
    int col = j*32 + lm;
    float br = bih[col] + bhh[col];
    float bz = bih[64+col] + bhh[64+col];
    float bin = bih[128+col], bhn = bhh[128+col];
    #pragma unroll
    for (int r=0;r<16;++r){
      int row = (r&3) + 8*(r>>2) + 4*hi;
      int n = n0 + row;
      int nc = min(n, NN-1);
      float rg = sigm(aF[j][r] + br);
      float z  = sigm(aF[2+j][r] + bz);
      float nn_ = tanhf(aIN[j][r] + bin + rg*(aHN[j][r] + bhn));
      float hold = hbuf[(size_t)nc*64 + col];
      float hnew = (1.0f - z)*nn_ + z*hold;
      if (n < NN) hbuf[(size_t)n*64 + col] = hnew;
    }
  }
}

// ---------------- fused Set2Set (6 iters) + memory LSTM + head (block per graph) ----------------
__global__ __launch_bounds__(256) void k_tail(
    const float* __restrict__ hbuf, const int* __restrict__ gst,
    float* __restrict__ ebuf,
    const float* __restrict__ swih, const float* __restrict__ swhh,
    const float* __restrict__ sbih, const float* __restrict__ sbhh,
    const float* __restrict__ mwih, const float* __restrict__ mbih,
    const float* __restrict__ mbhh, const float* __restrict__ l1w,
    const float* __restrict__ l1b, const float* __restrict__ l3w,
    const float* __restrict__ l3b, float* __restrict__ out){
  const int g = blockIdx.x, t = threadIdx.x;
  const int start = gst[g], end = gst[g+1];
  const int lane = t & 63, wv = t >> 6;
  __shared__ float qsh[128];
  __shared__ float hsh[64], csh[64];
  __shared__ float gat[512];
  __shared__ float red[256];
  __shared__ float rpart[4][64];
  __shared__ float hm[128], o1[64];
  if (t < 128) qsh[t] = 0.f;
  if (t < 64){ hsh[t] = 0.f; csh[t] = 0.f; }
  for (int it = 0; it < 6; ++it){
    __syncthreads();
    // Set2Set LSTM gates [256] = [i|f|g|o] x 64
    {
      float s = sbih[t] + sbhh[t];
      const float* wr = swih + (size_t)t*128;
      #pragma unroll 4
      for (int k=0;k<128;k++) s = fmaf(qsh[k], wr[k], s);
      const float* hr = swhh + (size_t)t*64;
      #pragma unroll 4
      for (int k=0;k<64;k++) s = fmaf(hsh[k], hr[k], s);
      gat[t] = s;
    }
    __syncthreads();
    if (t < 64){
      float ii = gat[t], ff = gat[64+t], gg = gat[128+t], oo = gat[192+t];
      float c = sigm(ff)*csh[t] + sigm(ii)*tanhf(gg);
      csh[t] = c;
      hsh[t] = sigm(oo)*tanhf(c);
    }
    __syncthreads();
    // segment softmax attention, q = hsh
    float lmax = -1e30f;
    for (int n = start + t; n < end; n += 256){
      const float4* row = (const float4*)(hbuf + (size_t)n*64);
      float s = 0.f;
      #pragma unroll
      for (int k=0;k<16;k++){
        float4 v = row[k];
        s += v.x*hsh[4*k] + v.y*hsh[4*k+1] + v.z*hsh[4*k+2] + v.w*hsh[4*k+3];
      }
      ebuf[n] = s;
      lmax = fmaxf(lmax, s);
    }
    red[t] = lmax; __syncthreads();
    for (int o2=128; o2>0; o2>>=1){ if (t<o2) red[t] = fmaxf(red[t], red[t+o2]); __syncthreads(); }
    const float gmax = red[0]; __syncthreads();
    float lsum = 0.f;
    for (int n = start + t; n < end; n += 256){
      float a = __expf(ebuf[n] - gmax);
      ebuf[n] = a;
      lsum += a;
    }
    red[t] = lsum; __syncthreads();
    for (int o2=128; o2>0; o2>>=1){ if (t<o2) red[t] += red[t+o2]; __syncthreads(); }
    const float inv = (red[0] > 0.f) ? 1.0f/red[0] : 0.f;
    float racc = 0.f;
    for (int n = start + wv; n < end; n += 4)
      racc = fmaf(ebuf[n], hbuf[(size_t)n*64 + lane], racc);
    rpart[wv][lane] = racc;
    __syncthreads();
    if (t < 64){
      qsh[t] = hsh[t];
      qsh[64+t] = (rpart[0][t] + rpart[1][t] + rpart[2][t] + rpart[3][t]) * inv;
    }
  }
  __syncthreads();
  // memory LSTM (hidden 128, h0=0) + lin1 + lin3
  for (int r = t; r < 512; r += 256){
    float s = mbih[r] + mbhh[r];
    const float* wr = mwih + (size_t)r*128;
    #pragma unroll 4
    for (int k=0;k<128;k++) s = fmaf(qsh[k], wr[k], s);
    gat[r] = s;
  }
  __syncthreads();
  if (t < 128){
    float c = sigm(gat[t]) * tanhf(gat[256+t]);
    float hmem = sigm(gat[384+t]) * tanhf(c);
    hm[t] = hmem;
    out[500 + g*128 + t] = hmem;
    out[64500 + g*128 + t] = c;
  }
  __syncthreads();
  if (t < 64){
    float s = l1b[t];
    const float* wr = l1w + (size_t)t*128;
    #pragma unroll 4
    for (int k=0;k<128;k++) s = fmaf(hm[k], wr[k], s);
    o1[t] = fmaxf(s, 0.f);
  }
  __syncthreads();
  if (t == 0){
    float v = l3b[0];
    for (int k=0;k<64;k++) v = fmaf(o1[k], l3w[k], v);
    out[g] = v;
  }
}

// ---------------- launch ----------------
extern "C" void kernel_launch(void* const* d_in, const int* in_sizes, int n_in,
                              void* d_out, int out_size, void* d_ws, size_t ws_size,
                              hipStream_t stream){
  (void)in_sizes; (void)n_in;
  const float* x     = (const float*)d_in[0];
  const int*   eidx  = (const int*)d_in[1];
  const float* eattr = (const float*)d_in[2];
  const int*   batch = (const int*)d_in[3];
  const float* lin0w = (const float*)d_in[4];
  const float* lin0b = (const float*)d_in[5];
  const float* mw1   = (const float*)d_in[6];
  const float* mb1   = (const float*)d_in[7];
  const float* mw2   = (const float*)d_in[8];
  const float* mb2   = (const float*)d_in[9];
  const float* convr = (const float*)d_in[10];
  const float* convb = (const float*)d_in[11];
  const float* gwih  = (const float*)d_in[12];
  const float* gwhh  = (const float*)d_in[13];
  const float* gbih  = (const float*)d_in[14];
  const float* gbhh  = (const float*)d_in[15];
  const float* swih  = (const float*)d_in[16];
  const float* swhh  = (const float*)d_in[17];
  const float* sbih  = (const float*)d_in[18];
  const float* sbhh  = (const float*)d_in[19];
  const float* mwih  = (const float*)d_in[20];
  const float* mbih  = (const float*)d_in[22];
  const float* mbhh  = (const float*)d_in[23];
  const float* l1w   = (const float*)d_in[24];
  const float* l1b   = (const float*)d_in[25];
  const float* l3w   = (const float*)d_in[26];
  const float* l3b   = (const float*)d_in[27];
  float* out = (float*)d_out;
  const int* src = eidx;
  const int* dstp = eidx + NE;

  size_t off = 0;
  auto take = [&](size_t bytes)->void*{
    void* p = (void*)((char*)d_ws + off);
    off = (off + bytes + 255) & ~(size_t)255;
    return p;
  };
  _Float16* h1T = (_Float16*)take((size_t)NKF*NEP*2);      // 27.2 MB
  _Float16* B2s = (_Float16*)take((size_t)NKF*8192);       // 1.1 MB
  _Float16* Wg  = (_Float16*)take((size_t)28672*2);        // 56 KB
  float* hbuf = (float*)take((size_t)NN*64*4);             // 12.8 MB
  float* agg  = (float*)take((size_t)NN*64*4);             // 12.8 MB
  float* deg  = (float*)take((size_t)NN*4);
  float* ebuf = (float*)take((size_t)NN*4);
  int*   gst  = (int*)take((size_t)(NB+1)*4);

  // Workspace guard (~55 MB plan). Stub signature if it fires: absmax 5.9204e-3.
  if (off > ws_size){
    hipMemsetAsync(d_out, 0, (size_t)out_size*4, stream);
    return;
  }

  hipMemsetAsync(h1T, 0, (size_t)NKF*NEP*2, stream);   // zero pad rows/cols
  hipMemsetAsync(deg, 0, (size_t)NN*4, stream);
  k_gstart<<<4, 128, 0, stream>>>(batch, gst);
  k_deg<<<(NE+255)/256, 256, 0, stream>>>(dstp, deg);
  k_rdeg<<<(NN+255)/256, 256, 0, stream>>>(deg);
  k_h1T<<<dim3((NE+255)/256, 129), 256, 0, stream>>>(eattr, mw1, mb1, h1T);
  k_lin0<<<NN*64/256, 256, 0, stream>>>(x, lin0w, lin0b, hbuf);
  k_prepB<<<(NKF*4096+255)/256, 256, 0, stream>>>(mw2, mb2, B2s);
  k_prepW<<<(28672+255)/256, 256, 0, stream>>>(convr, gwih, gwhh, Wg);

  for (int step = 0; step < 6; ++step){
    hipMemsetAsync(agg, 0, (size_t)NN*64*4, stream);
    k_msgemm2<<<NEP/256, 256, 0, stream>>>(h1T, B2s, hbuf, src, dstp, agg);
    k_node2<<<(NN+127)/128, 256, 0, stream>>>(agg, deg, hbuf, Wg, convb, gbih, gbhh);
  }

  k_tail<<<NB, 256, 0, stream>>>(hbuf, gst, ebuf, swih, swhh, sbih, sbhh,
                                 mwih, mbih, mbhh, l1w, l1b, l3w, l3b, out);
}

// Round 10
// 1170.895 us; speedup vs baseline: 1.0549x; 1.0549x over previous
//
#include <hip/hip_runtime.h>

#define NN 50000
#define NE 100000
#define NB 500
#define NEP 100096   // 391*256 padded edge count
#define NKF 136      // 34 chunks of 4 (129 real kf rows: 128 + bias)
#define CKF 4

typedef _Float16 half2_t __attribute__((ext_vector_type(2)));
typedef _Float16 half8_t __attribute__((ext_vector_type(8)));
typedef float f32x16 __attribute__((ext_vector_type(16)));

union F8U { half8_t v; uint4 u; };

__device__ __forceinline__ float sigm(float x){ return 1.0f/(1.0f + __expf(-x)); }
__device__ __forceinline__ unsigned short f16u(float f){
  _Float16 h = (_Float16)f; return *(unsigned short*)&h;
}

// ---------------- setup kernels ----------------

__global__ void k_gstart(const int* __restrict__ batch, int* __restrict__ gst){
  int g = blockIdx.x*blockDim.x + threadIdx.x;
  if (g > NB) return;
  if (g == NB){ gst[g] = NN; return; }
  int lo=0, hi=NN;
  while (lo < hi){ int mid=(lo+hi)>>1; if (batch[mid] < g) lo = mid+1; else hi = mid; }
  gst[g] = lo;
}

__global__ void k_deg(const int* __restrict__ dst, float* __restrict__ deg){
  int e = blockIdx.x*blockDim.x + threadIdx.x;
  if (e < NE) atomicAdd(&deg[dst[e]], 1.0f);
}

__global__ void k_rdeg(float* __restrict__ deg){
  int i = blockIdx.x*blockDim.x + threadIdx.x;
  if (i < NN) deg[i] = 1.0f / fmaxf(deg[i], 1.0f);
}

// h1T[j][e] = relu(edge_attr[e] @ w1[j] + b1[j]); row 128 = 1.0 (bias slice)
__global__ void k_h1T(const float* __restrict__ ea, const float* __restrict__ w1,
                      const float* __restrict__ b1, _Float16* __restrict__ h1T){
  int e = blockIdx.x*256 + threadIdx.x;
  int j = blockIdx.y;
  if (e >= NE) return;
  float s;
  if (j == 128){
    s = 1.0f;
  } else {
    const float* a = ea + (size_t)e*7;
    const float* wr = w1 + j*7;
    s = b1[j];
    #pragma unroll
    for (int k=0;k<7;k++) s = fmaf(a[k], wr[k], s);
    s = fmaxf(s, 0.0f);
  }
  h1T[(size_t)j*NEP + e] = (_Float16)s;
}

// out0 = relu(x @ lin0_w.T + b)  [N,64]
__global__ void k_lin0(const float* __restrict__ x, const float* __restrict__ w,
                       const float* __restrict__ b, float* __restrict__ hbuf){
  int idx = blockIdx.x*blockDim.x + threadIdx.x;
  if (idx >= NN*64) return;
  int n = idx >> 6, o = idx & 63;
  const float* xr = x + n*3;
  const float* wr = w + o*3;
  float s = b[o] + xr[0]*wr[0] + xr[1]*wr[1] + xr[2]*wr[2];
  hbuf[idx] = fmaxf(s, 0.0f);
}

// B2s[kf] is an 8KB block: [o=64][i=64] f16, XOR-swizzled byte^((o&7)<<4).
// kf<128: w2[(i*64+o), kf]; kf==128: b2[i*64+o]; kf in 129..135: 0 (pad).
__global__ void k_prepB(const float* __restrict__ w2, const float* __restrict__ b2,
                        _Float16* __restrict__ B2s){
  int idx = blockIdx.x*blockDim.x + threadIdx.x;
  if (idx >= NKF*4096) return;
  int kf = idx >> 12, r = idx & 4095, o = r >> 6, i = r & 63;
  float v = (kf < 128) ? w2[(size_t)(i*64+o)*128 + kf] : (kf == 128 ? b2[i*64+o] : 0.0f);
  int byt = (o*128 + i*2) ^ ((o&7)<<4);
  *(unsigned short*)((char*)B2s + (size_t)kf*8192 + byt) = f16u(v);
}

// Wg = [rootB 8KB][WG 48KB] f16, swizzled.
__global__ void k_prepW(const float* __restrict__ root, const float* __restrict__ wih,
                        const float* __restrict__ whh, _Float16* __restrict__ Wg){
  int idx = blockIdx.x*blockDim.x + threadIdx.x;
  if (idx >= 28672) return;
  if (idx < 4096){
    int o = idx >> 6, k = idx & 63;
    int byt = (o*128 + k*2) ^ ((o&7)<<4);
    *(unsigned short*)((char*)Wg + byt) = f16u(root[k*64 + o]);
  } else {
    int x = idx - 4096;
    int o = x >> 7, k = x & 127;
    float v = (k < 64) ? wih[o*64 + k] : whh[o*64 + (k-64)];
    int byt = (o*256 + k*2) ^ ((o&7)<<4);
    *(unsigned short*)((char*)Wg + 8192 + byt) = f16u(v);
  }
}

// cw[t][k] = combined Set2Set gate weight: k<64: swih[t][k]+swhh[t][k]; k>=64: swih[t][k]
// (valid because q_star[0:64] == hs at every iteration)
__global__ void k_prepS(const float* __restrict__ swih, const float* __restrict__ swhh,
                        float* __restrict__ cw){
  int idx = blockIdx.x*blockDim.x + threadIdx.x;
  if (idx >= 256*128) return;
  int t = idx >> 7, k = idx & 127;
  float v = swih[(size_t)t*128 + k];
  if (k < 64) v += swhh[(size_t)t*64 + k];
  cw[idx] = v;
}

// ---------------- fused NNConv message GEMM v2 (LDS-staged, NT=4, CKF=4) ----------------
__global__ __launch_bounds__(256) void k_msgemm2(
    const _Float16* __restrict__ h1T, const _Float16* __restrict__ B2s,
    const float* __restrict__ hbuf, const int* __restrict__ src,
    const int* __restrict__ dst, float* __restrict__ agg){
  __shared__ __align__(16) _Float16 Bsh[CKF*4096];   // 32KB
  __shared__ __align__(16) _Float16 h1sh[CKF*256];   // 2KB [kf][e_local]
  __shared__ int dst_s[256];
  const int t = threadIdx.x;
  const int lane = t & 63, wv = t >> 6;
  const int hi = lane >> 5, lm = lane & 31;
  const int we = wv >> 1, wo = wv & 1;
  const int o0 = wo * 32;
  const int e0 = blockIdx.x * 256;
  {
    int eg = e0 + t;
    dst_s[t] = (eg < NE) ? dst[eg] : -1;
  }
  half8_t xa[4][4];
  #pragma unroll
  for (int tt=0; tt<4; ++tt){
    int eg = e0 + tt*64 + we*32 + lm;
    int sidx = (eg < NE) ? src[eg] : 0;
    const float4* xr = (const float4*)(hbuf + (size_t)sidx*64);
    #pragma unroll
    for (int q=0;q<4;++q){
      float4 a = xr[q*4 + hi*2];
      float4 b = xr[q*4 + hi*2 + 1];
      half8_t h;
      h[0]=(_Float16)a.x; h[1]=(_Float16)a.y; h[2]=(_Float16)a.z; h[3]=(_Float16)a.w;
      h[4]=(_Float16)b.x; h[5]=(_Float16)b.y; h[6]=(_Float16)b.z; h[7]=(_Float16)b.w;
      xa[tt][q] = h;
    }
  }
  f32x16 acc[4] = {};
  for (int c = 0; c < NKF/CKF; ++c){
    __syncthreads();
    const char* gB = (const char*)B2s + (size_t)c*(CKF*8192);
    #pragma unroll 4
    for (int r=0;r<8;++r){
      uint4 u = *(const uint4*)(gB + r*4096 + t*16);
      *(uint4*)((char*)Bsh + r*4096 + t*16) = u;
    }
    if (t < 128){
      int rr = t >> 5, cc = t & 31;
      uint4 u = *(const uint4*)((const char*)h1T + ((size_t)(c*CKF+rr)*NEP + (size_t)e0)*2 + cc*16);
      *(uint4*)((char*)h1sh + rr*512 + cc*16) = u;
    }
    __syncthreads();
    #pragma unroll
    for (int kf=0; kf<CKF; ++kf){
      _Float16 hv0 = h1sh[kf*256 +       we*32 + lm];
      _Float16 hv1 = h1sh[kf*256 +  64 + we*32 + lm];
      _Float16 hv2 = h1sh[kf*256 + 128 + we*32 + lm];
      _Float16 hv3 = h1sh[kf*256 + 192 + we*32 + lm];
      half8_t b0 = {hv0,hv0,hv0,hv0,hv0,hv0,hv0,hv0};
      half8_t b1 = {hv1,hv1,hv1,hv1,hv1,hv1,hv1,hv1};
      half8_t b2_ = {hv2,hv2,hv2,hv2,hv2,hv2,hv2,hv2};
      half8_t b3 = {hv3,hv3,hv3,hv3,hv3,hv3,hv3,hv3};
      #pragma unroll
      for (int q=0;q<4;++q){
        F8U bf;
        int byt = (((o0+lm)*128 + q*32 + hi*16) ^ ((lm&7)<<4));
        bf.u = *(const uint4*)((const char*)Bsh + kf*8192 + byt);
        acc[0] = __builtin_amdgcn_mfma_f32_32x32x16_f16(xa[0][q]*b0, bf.v, acc[0], 0,0,0);
        acc[1] = __builtin_amdgcn_mfma_f32_32x32x16_f16(xa[1][q]*b1, bf.v, acc[1], 0,0,0);
        acc[2] = __builtin_amdgcn_mfma_f32_32x32x16_f16(xa[2][q]*b2_, bf.v, acc[2], 0,0,0);
        acc[3] = __builtin_amdgcn_mfma_f32_32x32x16_f16(xa[3][q]*b3, bf.v, acc[3], 0,0,0);
      }
    }
  }
  #pragma unroll
  for (int tt=0;tt<4;++tt){
    #pragma unroll
    for (int r=0;r<16;++r){
      int row = (r&3) + 8*(r>>2) + 4*hi;
      int d = dst_s[tt*64 + we*32 + row];
      if (d >= 0) atomicAdd(&agg[(size_t)d*64 + o0 + lm], acc[tt][r]);
    }
  }
}

// ---------------- node update v2: MFMA NNConv-epilogue + GRU ----------------
__global__ __launch_bounds__(256) void k_node2(
    const float* __restrict__ agg, const float* __restrict__ rdeg,
    float* __restrict__ hbuf, const _Float16* __restrict__ Wg,
    const float* __restrict__ cbias, const float* __restrict__ bih,
    const float* __restrict__ bhh){
  __shared__ __align__(16) _Float16 WB[28672];
  __shared__ __align__(16) _Float16 mT[4][2048];
  const int t = threadIdx.x;
  const int lane = t & 63, wv = t >> 6;
  const int hi = lane >> 5, lm = lane & 31;
  #pragma unroll 2
  for (int r=0;r<14;++r){
    uint4 u = *(const uint4*)((const char*)Wg + r*4096 + t*16);
    *(uint4*)((char*)WB + r*4096 + t*16) = u;
  }
  const int n0 = blockIdx.x*128 + wv*32;
  half8_t ah[4];
  {
    int nr = min(n0 + lm, NN-1);
    const float4* hr = (const float4*)(hbuf + (size_t)nr*64);
    #pragma unroll
    for (int q=0;q<4;++q){
      float4 a = hr[q*4 + hi*2];
      float4 b = hr[q*4 + hi*2 + 1];
      half8_t h;
      h[0]=(_Float16)a.x; h[1]=(_Float16)a.y; h[2]=(_Float16)a.z; h[3]=(_Float16)a.w;
      h[4]=(_Float16)b.x; h[5]=(_Float16)b.y; h[6]=(_Float16)b.z; h[7]=(_Float16)b.w;
      ah[q] = h;
    }
  }
  __syncthreads();
  f32x16 am[2] = {};
  #pragma unroll
  for (int q=0;q<4;++q){
    #pragma unroll
    for (int ot=0;ot<2;++ot){
      int o = ot*32 + lm;
      F8U bf;
      bf.u = *(const uint4*)((const char*)WB + ((o*128 + q*32 + hi*16) ^ ((o&7)<<4)));
      am[ot] = __builtin_amdgcn_mfma_f32_32x32x16_f16(ah[q], bf.v, am[ot], 0,0,0);
    }
  }
  #pragma unroll
  for (int ot=0;ot<2;++ot){
    int col = ot*32 + lm;
    float cb = cbias[col];
    #pragma unroll
    for (int r=0;r<16;++r){
      int row = (r&3) + 8*(r>>2) + 4*hi;
      int n = min(n0 + row, NN-1);
      float mv = fmaxf(fmaf(agg[(size_t)n*64 + col], rdeg[n], am[ot][r] + cb), 0.0f);
      *(unsigned short*)((char*)&mT[wv][0] + ((row*128 + col*2) ^ ((row&7)<<4))) = f16u(mv);
    }
  }
  __syncthreads();
  half8_t amf[4];
  #pragma unroll
  for (int q=0;q<4;++q){
    F8U v;
    v.u = *(const uint4*)((const char*)&mT[wv][0] + ((lm*128 + q*32 + hi*16) ^ ((lm&7)<<4)));
    amf[q] = v.v;
  }
  f32x16 aF[4] = {}; f32x16 aIN[2] = {}; f32x16 aHN[2] = {};
  const char* WGp = (const char*)WB + 8192;
  #pragma unroll
  for (int q=0;q<4;++q){
    #pragma unroll
    for (int ot=0;ot<4;++ot){
      int o = ot*32 + lm;
      F8U bf; bf.u = *(const uint4*)(WGp + ((o*256 + q*32 + hi*16) ^ ((o&7)<<4)));
      aF[ot] = __builtin_amdgcn_mfma_f32_32x32x16_f16(amf[q], bf.v, aF[ot], 0,0,0);
    }
    #pragma unroll
    for (int j=0;j<2;++j){
      int o = (4+j)*32 + lm;
      F8U bf; bf.u = *(const uint4*)(WGp + ((o*256 + q*32 + hi*16) ^ ((o&7)<<4)));
      aIN[j] = __builtin_amdgcn_mfma_f32_32x32x16_f16(amf[q], bf.v, aIN[j], 0,0,0);
    }
  }
  #pragma unroll
  for (int q=0;q<4;++q){
    #pragma unroll
    for (int ot=0;ot<4;++ot){
      int o = ot*32 + lm;
      F8U bf; bf.u = *(const uint4*)(WGp + ((o*256 + 128 + q*32 + hi*16) ^ ((o&7)<<4)));
      aF[ot] = __builtin_amdgcn_mfma_f32_32x32x16_f16(ah[q], bf.v, aF[ot], 0,0,0);
    }
    #pragma unroll
    for (int j=0;j<2;++j){
      int o = (4+j)*32 + lm;
      F8U bf; bf.u = *(const uint4*)(WGp + ((o*256 + 128 + q*32 + hi*16) ^ ((o&7)<<4)));
      aHN[j] = __builtin_amdgcn_mfma_f32_32x32x16_f16(ah[q], bf.v, aHN[j], 0,0,0);
    }
  }
  #pragma unroll
  for (int j=0;j<2;++j){
    int col = j*32 + lm;
    float br = bih[col] + bhh[col];
    float bz = bih[64+col] + bhh[64+col];
    float bin = bih[128+col], bhn = bhh[128+col];
    #pragma unroll
    for (int r=0;r<16;++r){
      int row = (r&3) + 8*(r>>2) + 4*hi;
      int n = n0 + row;
      int nc = min(n, NN-1);
      float rg = sigm(aF[j][r] + br);
      float z  = sigm(aF[2+j][r] + bz);
      float nn_ = tanhf(aIN[j][r] + bin + rg*(aHN[j][r] + bhn));
      float hold = hbuf[(size_t)nc*64 + col];
      float hnew = (1.0f - z)*nn_ + z*hold;
      if (n < NN) hbuf[(size_t)n*64 + col] = hnew;
    }
  }
}

// ---------------- fused Set2Set (6 iters) + memory LSTM + head, v2 ----------------
// Combined gate weights staged in LDS once (conflict-free stride-129), wave shfl
// reductions, vectorized mem-LSTM/lin1. ~137KB LDS -> 1 block/CU.
__global__ __launch_bounds__(256) void k_tail(
    const float* __restrict__ hbuf, const int* __restrict__ gst,
    float* __restrict__ ebuf, const float* __restrict__ cw,
    const float* __restrict__ sbih, const float* __restrict__ sbhh,
    const float* __restrict__ mwih, const float* __restrict__ mbih,
    const float* __restrict__ mbhh, const float* __restrict__ l1w,
    const float* __restrict__ l1b, const float* __restrict__ l3w,
    const float* __restrict__ l3b, float* __restrict__ out){
  __shared__ float Ws[256*129];                 // 132KB combined gate weights
  __shared__ __align__(16) float hsr[128];      // [hs | r]
  __shared__ float hs[64], cs[64];
  __shared__ float gat[512];
  __shared__ float red[4];
  __shared__ __align__(16) float rpart[4][64];
  __shared__ __align__(16) float hm[128];
  __shared__ __align__(16) float o1[64];
  const int g = blockIdx.x, t = threadIdx.x;
  const int start = gst[g], end = gst[g+1];
  const int lane = t & 63, wv = t >> 6;
  for (int idx = t; idx < 256*128; idx += 256){
    int r = idx >> 7, k = idx & 127;
    Ws[r*129 + k] = cw[idx];
  }
  if (t < 128) hsr[t] = 0.f;
  if (t < 64){ hs[t] = 0.f; cs[t] = 0.f; }
  const float bs = sbih[t] + sbhh[t];
  __syncthreads();
  for (int it = 0; it < 6; ++it){
    // gates[t] = bs + sum_k hsr[k] * Ws[t][k]
    {
      float s = bs;
      const float* wr = &Ws[t*129];
      const float4* h4 = (const float4*)hsr;
      #pragma unroll
      for (int k4=0;k4<32;k4++){
        float4 q = h4[k4];
        s = fmaf(q.x, wr[4*k4],   s);
        s = fmaf(q.y, wr[4*k4+1], s);
        s = fmaf(q.z, wr[4*k4+2], s);
        s = fmaf(q.w, wr[4*k4+3], s);
      }
      gat[t] = s;
    }
    __syncthreads();
    if (t < 64){
      float ii = gat[t], ff = gat[64+t], gg = gat[128+t], oo = gat[192+t];
      float c = sigm(ff)*cs[t] + sigm(ii)*tanhf(gg);
      cs[t] = c;
      hs[t] = sigm(oo)*tanhf(c);
    }
    __syncthreads();
    // attention: scores + max
    float lmax = -1e30f;
    for (int n = start + t; n < end; n += 256){
      const float4* row = (const float4*)(hbuf + (size_t)n*64);
      float sc = 0.f;
      #pragma unroll
      for (int k=0;k<16;k++){
        float4 v = row[k];
        sc += v.x*hs[4*k] + v.y*hs[4*k+1] + v.z*hs[4*k+2] + v.w*hs[4*k+3];
      }
      ebuf[n] = sc;
      lmax = fmaxf(lmax, sc);
    }
    #pragma unroll
    for (int m=1;m<64;m<<=1) lmax = fmaxf(lmax, __shfl_xor(lmax, m));
    if (lane == 0) red[wv] = lmax;
    __syncthreads();
    const float gmax = fmaxf(fmaxf(red[0],red[1]), fmaxf(red[2],red[3]));
    __syncthreads();                               // red reused for sum below
    float lsum = 0.f;
    for (int n = start + t; n < end; n += 256){
      float a = __expf(ebuf[n] - gmax);
      ebuf[n] = a;
      lsum += a;
    }
    #pragma unroll
    for (int m=1;m<64;m<<=1) lsum += __shfl_xor(lsum, m);
    if (lane == 0) red[wv] = lsum;
    __syncthreads();
    const float tot = red[0]+red[1]+red[2]+red[3];
    const float inv = (tot > 0.f) ? 1.0f/tot : 0.f;
    float racc = 0.f;
    for (int n = start + wv; n < end; n += 4)
      racc = fmaf(ebuf[n], hbuf[(size_t)n*64 + lane], racc);
    rpart[wv][lane] = racc;
    __syncthreads();
    if (t < 64){
      hsr[t] = hs[t];
      hsr[64+t] = (rpart[0][t]+rpart[1][t]+rpart[2][t]+rpart[3][t]) * inv;
    }
    __syncthreads();
  }
  // memory LSTM (q_star = hsr), vectorized: 2 gate rows per thread
  {
    const float4* q4 = (const float4*)hsr;
    #pragma unroll
    for (int rr=0; rr<2; ++rr){
      int r = t + rr*256;
      const float4* wr = (const float4*)(mwih + (size_t)r*128);
      float4 a = make_float4(0.f,0.f,0.f,0.f);
      #pragma unroll
      for (int k=0;k<32;k++){
        float4 w = wr[k]; float4 q = q4[k];
        a.x = fmaf(w.x,q.x,a.x); a.y = fmaf(w.y,q.y,a.y);
        a.z = fmaf(w.z,q.z,a.z); a.w = fmaf(w.w,q.w,a.w);
      }
      gat[r] = a.x+a.y+a.z+a.w + mbih[r] + mbhh[r];
    }
  }
  __syncthreads();
  if (t < 128){
    float c = sigm(gat[t]) * tanhf(gat[256+t]);
    float hmem = sigm(gat[384+t]) * tanhf(c);
    hm[t] = hmem;
    out[500 + g*128 + t] = hmem;
    out[64500 + g*128 + t] = c;
  }
  __syncthreads();
  if (t < 64){
    const float4* wr = (const float4*)(l1w + (size_t)t*128);
    const float4* h4 = (const float4*)hm;
    float4 a = make_float4(0.f,0.f,0.f,0.f);
    #pragma unroll
    for (int k=0;k<32;k++){
      float4 w = wr[k]; float4 q = h4[k];
      a.x = fmaf(w.x,q.x,a.x); a.y = fmaf(w.y,q.y,a.y);
      a.z = fmaf(w.z,q.z,a.z); a.w = fmaf(w.w,q.w,a.w);
    }
    o1[t] = fmaxf(a.x+a.y+a.z+a.w + l1b[t], 0.f);
  }
  __syncthreads();
  if (t == 0){
    float v = l3b[0];
    for (int k=0;k<64;k++) v = fmaf(o1[k], l3w[k], v);
    out[g] = v;
  }
}

// ---------------- launch ----------------
extern "C" void kernel_launch(void* const* d_in, const int* in_sizes, int n_in,
                              void* d_out, int out_size, void* d_ws, size_t ws_size,
                              hipStream_t stream){
  (void)in_sizes; (void)n_in;
  const float* x     = (const float*)d_in[0];
  const int*   eidx  = (const int*)d_in[1];
  const float* eattr = (const float*)d_in[2];
  const int*   batch = (const int*)d_in[3];
  const float* lin0w = (const float*)d_in[4];
  const float* lin0b = (const float*)d_in[5];
  const float* mw1   = (const float*)d_in[6];
  const float* mb1   = (const float*)d_in[7];
  const float* mw2   = (const float*)d_in[8];
  const float* mb2   = (const float*)d_in[9];
  const float* convr = (const float*)d_in[10];
  const float* convb = (const float*)d_in[11];
  const float* gwih  = (const float*)d_in[12];
  const float* gwhh  = (const float*)d_in[13];
  const float* gbih  = (const float*)d_in[14];
  const float* gbhh  = (const float*)d_in[15];
  const float* swih  = (const float*)d_in[16];
  const float* swhh  = (const float*)d_in[17];
  const float* sbih  = (const float*)d_in[18];
  const float* sbhh  = (const float*)d_in[19];
  const float* mwih  = (const float*)d_in[20];
  const float* mbih  = (const float*)d_in[22];
  const float* mbhh  = (const float*)d_in[23];
  const float* l1w   = (const float*)d_in[24];
  const float* l1b   = (const float*)d_in[25];
  const float* l3w   = (const float*)d_in[26];
  const float* l3b   = (const float*)d_in[27];
  float* out = (float*)d_out;
  const int* src = eidx;
  const int* dstp = eidx + NE;

  size_t off = 0;
  auto take = [&](size_t bytes)->void*{
    void* p = (void*)((char*)d_ws + off);
    off = (off + bytes + 255) & ~(size_t)255;
    return p;
  };
  _Float16* h1T = (_Float16*)take((size_t)NKF*NEP*2);      // 27.2 MB
  _Float16* B2s = (_Float16*)take((size_t)NKF*8192);       // 1.1 MB
  _Float16* Wg  = (_Float16*)take((size_t)28672*2);        // 56 KB
  float* cw   = (float*)take((size_t)256*128*4);           // 128 KB
  float* hbuf = (float*)take((size_t)NN*64*4);             // 12.8 MB
  float* agg  = (float*)take((size_t)NN*64*4);             // 12.8 MB
  float* deg  = (float*)take((size_t)NN*4);
  float* ebuf = (float*)take((size_t)NN*4);
  int*   gst  = (int*)take((size_t)(NB+1)*4);

  // Workspace guard (~55 MB plan). Stub signature if it fires: absmax 5.9204e-3.
  if (off > ws_size){
    hipMemsetAsync(d_out, 0, (size_t)out_size*4, stream);
    return;
  }

  hipMemsetAsync(h1T, 0, (size_t)NKF*NEP*2, stream);   // zero pad rows/cols
  hipMemsetAsync(deg, 0, (size_t)NN*4, stream);
  k_gstart<<<4, 128, 0, stream>>>(batch, gst);
  k_deg<<<(NE+255)/256, 256, 0, stream>>>(dstp, deg);
  k_rdeg<<<(NN+255)/256, 256, 0, stream>>>(deg);
  k_h1T<<<dim3((NE+255)/256, 129), 256, 0, stream>>>(eattr, mw1, mb1, h1T);
  k_lin0<<<NN*64/256, 256, 0, stream>>>(x, lin0w, lin0b, hbuf);
  k_prepB<<<(NKF*4096+255)/256, 256, 0, stream>>>(mw2, mb2, B2s);
  k_prepW<<<(28672+255)/256, 256, 0, stream>>>(convr, gwih, gwhh, Wg);
  k_prepS<<<128, 256, 0, stream>>>(swih, swhh, cw);

  for (int step = 0; step < 6; ++step){
    hipMemsetAsync(agg, 0, (size_t)NN*64*4, stream);
    k_msgemm2<<<NEP/256, 256, 0, stream>>>(h1T, B2s, hbuf, src, dstp, agg);
    k_node2<<<(NN+127)/128, 256, 0, stream>>>(agg, deg, hbuf, Wg, convb, gbih, gbhh);
  }

  k_tail<<<NB, 256, 0, stream>>>(hbuf, gst, ebuf, cw, sbih, sbhh,
                                 mwih, mbih, mbhh, l1w, l1b, l3w, l3b, out);
}